// Round 5
// baseline (396.557 us; speedup 1.0000x reference)
//
#include <hip/hip_runtime.h>

#define N_NODES 50000
#define N_EDGES 800000
#define DIM     128
#define NGRAPH  128
#define NCLASS  10
#define NLAYER  4

#define TEAMS   256
#define ESLICE  (N_EDGES / TEAMS)    // 3125 edges per team slice
#define CWORDS  12500                // 50000 nodes / 4 (nibble-packed bytes per word)

typedef __attribute__((ext_vector_type(8))) short short8;
typedef __attribute__((ext_vector_type(4))) float floatx4;

__device__ __forceinline__ unsigned f2bf(float f) {
    union { float f; unsigned u; } v; v.f = f;
    return (v.u + 0x7fffu + ((v.u >> 16) & 1u)) >> 16;   // RNE
}
__device__ __forceinline__ float bf_lo(unsigned u) { return __uint_as_float(u << 16); }
__device__ __forceinline__ float bf_hi(unsigned u) { return __uint_as_float(u & 0xffff0000u); }

// ---------------------------------------------------------------------------
// Pass 1: per-team-slice nibble histograms (in=low nibble, out=high nibble,
// one byte per node). Each edge read exactly once. Coalesced writeback.
__global__ __launch_bounds__(1024) void count_kernel(
    const int* __restrict__ ei, unsigned* __restrict__ cntw)
{
    __shared__ unsigned h[CWORDS];      // 50 KB
    int team = blockIdx.x, tid = threadIdx.x;
    for (int i = tid; i < CWORDS; i += 1024) h[i] = 0;
    __syncthreads();
    const int e0 = team * ESLICE;
    const int* __restrict__ srcp = ei;
    const int* __restrict__ dstp = ei + N_EDGES;
    for (int e = e0 + tid; e < e0 + ESLICE; e += 1024) {
        int s = srcp[e], d = dstp[e];
        atomicAdd(&h[d >> 2], 1u  << (8 * (d & 3)));   // in-count  (low nibble)
        atomicAdd(&h[s >> 2], 16u << (8 * (s & 3)));   // out-count (high nibble)
    }
    __syncthreads();
    for (int i = tid; i < CWORDS; i += 1024)
        cntw[(size_t)team * CWORDS + i] = h[i];
}

// Pass 2: per-node exclusive prefix over the 256 team counts -> exact slot
// offsets; also emits total degrees -> cnt_dense, c_src, c_dst.
// 256-node tile per block; two 128-team phases (32 KB + 32 KB LDS).
__global__ __launch_bounds__(1024) void offsets_kernel(
    const unsigned* __restrict__ cntw, unsigned* __restrict__ offsw,
    unsigned* __restrict__ cnt_dense, float* __restrict__ c_src,
    float* __restrict__ c_dst)
{
    __shared__ unsigned ldsC[128 * 64];   // counts tile
    __shared__ unsigned ldsO[128 * 64];   // offsets tile
    int tid = threadIdx.x;
    int n0 = blockIdx.x * 256;
    int w0 = n0 >> 2;
    unsigned indeg = 0, outdeg = 0;
    for (int ph = 0; ph < 2; ++ph) {
        int t0 = ph * 128;
        for (int i = tid; i < 128 * 64; i += 1024) {
            int tl = i >> 6, wl = i & 63;
            int gw = w0 + wl;
            ldsC[i] = (gw < CWORDS) ? cntw[(size_t)(t0 + tl) * CWORDS + gw] : 0u;
        }
        __syncthreads();
        if (tid < 256) {
            unsigned char* ob = (unsigned char*)ldsO;
            for (int tl = 0; tl < 128; ++tl) {
                unsigned wv = ldsC[tl * 64 + (tid >> 2)];
                unsigned b = (wv >> (8 * (tid & 3))) & 255u;
                ob[tl * 256 + tid] = (unsigned char)indeg;  // exclusive prefix
                indeg  += (b & 15u);
                outdeg += (b >> 4);
            }
        }
        __syncthreads();
        for (int i = tid; i < 128 * 64; i += 1024) {
            int tl = i >> 6, wl = i & 63;
            int gw = w0 + wl;
            if (gw < CWORDS) offsw[(size_t)(t0 + tl) * CWORDS + gw] = ldsO[i];
        }
        __syncthreads();
    }
    if (tid < 256) {
        int n = n0 + tid;
        if (n < N_NODES) {
            unsigned id_ = indeg, od = outdeg;
            cnt_dense[n] = id_ > 64u ? 64u : id_;
            if (id_ < 1u) id_ = 1u;
            if (od < 1u) od = 1u;
            c_dst[n] = 1.0f / sqrtf((float)id_);
            c_src[n] = 1.0f / sqrtf((float)od);
        }
    }
}

// Pass 3: rescan slice, LDS position counters give unique local pos; write
// src directly into dense CSR at offs(team,d)+pos.
__global__ __launch_bounds__(1024) void scatter_kernel(
    const int* __restrict__ ei, const unsigned* __restrict__ offsw,
    unsigned* __restrict__ colc)
{
    __shared__ unsigned h[CWORDS];      // 50 KB pos counters (low nibble)
    int team = blockIdx.x, tid = threadIdx.x;
    for (int i = tid; i < CWORDS; i += 1024) h[i] = 0;
    __syncthreads();
    const unsigned char* __restrict__ ob =
        (const unsigned char*)offsw + (size_t)team * 50000;
    const int e0 = team * ESLICE;
    const int* __restrict__ srcp = ei;
    const int* __restrict__ dstp = ei + N_EDGES;
    for (int e = e0 + tid; e < e0 + ESLICE; e += 1024) {
        int s = srcp[e], d = dstp[e];
        unsigned old = atomicAdd(&h[d >> 2], 1u << (8 * (d & 3)));
        unsigned pos = (old >> (8 * (d & 3))) & 15u;
        unsigned slot = (unsigned)ob[d] + pos;
        if (slot < 64u) colc[(size_t)d * 64 + slot] = (unsigned)s;
    }
}

// hs(bf16 pairs) = x * c_src[row]
__global__ __launch_bounds__(256) void prescale_kernel(
    const float2* __restrict__ x, const float* __restrict__ c_src,
    unsigned* __restrict__ hs)
{
    int i = blockIdx.x * blockDim.x + threadIdx.x;   // over N*64 uints
    if (i >= N_NODES * 64) return;
    int row = i >> 6;
    float c = c_src[row];
    float2 v = x[i];
    hs[i] = f2bf(v.x * c) | (f2bf(v.y * c) << 16);
}

// Quarter-split gather: 16 lanes per (node, quarter), 4 groups per wave.
// Tasks quarter-major so each 3.2 MB quarter working set is L2-resident.
__global__ __launch_bounds__(256) void aggregate_kernel(
    const unsigned* __restrict__ hs, const uint4* __restrict__ colc4,
    const unsigned* __restrict__ cnt_dense, unsigned* __restrict__ m)
{
    int wid  = (blockIdx.x * blockDim.x + threadIdx.x) >> 6;   // 0..49999
    int lane = threadIdx.x & 63;
    int g = lane >> 4, t = lane & 15;
    int base = wid * 4;                 // quartet of tasks, same quarter
    int q = base / N_NODES;             // quarter 0..3 (N divisible by 4)
    int n = (base % N_NODES) + g;
    int qo = q << 4;                    // uint offset of quarter in row

    unsigned deg = cnt_dense[n];
    uint4 idx4 = colc4[(size_t)n * 16 + t];   // lane t holds indices 4t..4t+3
    unsigned jm = max(deg, (unsigned)__shfl_xor((int)deg, 16));
    jm = max(jm, (unsigned)__shfl_xor((int)jm, 32));
    const unsigned* iv = (const unsigned*)&idx4;
    float ax = 0.f, ay = 0.f;
    for (unsigned j = 0; j < jm; j += 4) {
#pragma unroll
        for (int k = 0; k < 4; ++k) {
            int sl = (g << 4) | (int)((j + k) >> 2);
            unsigned s = (unsigned)__shfl((int)iv[k], sl);  // comp (j+k)&3 == k
            s = (s < N_NODES) ? s : 0u;
            unsigned u = hs[(size_t)s * 64 + qo + t];       // 64 B per group
            bool v = (j + k) < deg;
            ax += v ? bf_lo(u) : 0.f;
            ay += v ? bf_hi(u) : 0.f;
        }
    }
    m[(size_t)n * 64 + qo + t] = f2bf(ax) | (f2bf(ay) << 16);
}

// Pre-swizzle W into MFMA B-fragment order, bf16.
__global__ __launch_bounds__(256) void wprep_kernel(
    const float* __restrict__ W0, const float* __restrict__ Ws,
    uint4* __restrict__ Wf)
{
    int t = blockIdx.x * blockDim.x + threadIdx.x;
    if (t >= NLAYER * 2048) return;
    int layer = t >> 11;
    int rem = t & 2047;
    int lane = rem & 63;
    int s = (rem >> 6) & 3;
    int c = rem >> 8;
    int quad = lane >> 4, colw = c * 16 + (lane & 15);
    int k0 = s * 32 + quad * 8;
    const float* W = (layer == 0) ? W0 : Ws + (size_t)(layer - 1) * DIM * DIM;
    uint4 p;
    unsigned* pp = (unsigned*)&p;
#pragma unroll
    for (int j = 0; j < 4; ++j) {
        unsigned lo = f2bf(W[(size_t)(k0 + 2 * j) * DIM + colw]);
        unsigned hi = f2bf(W[(size_t)(k0 + 2 * j + 1) * DIM + colw]);
        pp[j] = lo | (hi << 16);
    }
    Wf[t] = p;
}

// Hout = relu(c_dst[r]*(M@W) + b) [* c_src[r] if !last], MFMA 16x16x32 bf16.
__global__ __launch_bounds__(256) void mfma_gemm_kernel(
    const uint4* __restrict__ Mb, const uint4* __restrict__ Wf,
    const float* __restrict__ bias, const float* __restrict__ c_dst,
    const float* __restrict__ c_src, unsigned short* __restrict__ out_bf,
    float* __restrict__ out_f32, int last)
{
    int tid = threadIdx.x;
    int wave = tid >> 6, lane = tid & 63;
    int quad = lane >> 4, m16 = lane & 15;
    int r0 = blockIdx.x * 64 + wave * 16;

    int rA = r0 + m16; if (rA >= N_NODES) rA = N_NODES - 1;
    const uint4* pA = Mb + (size_t)rA * 16 + quad;
    union U { uint4 u; short8 s; };
    U a[4];
#pragma unroll
    for (int s = 0; s < 4; ++s) a[s].u = pA[s * 4];

    floatx4 acc[8];
#pragma unroll
    for (int c = 0; c < 8; ++c) {
        floatx4 ac = {0.f, 0.f, 0.f, 0.f};
#pragma unroll
        for (int s = 0; s < 4; ++s) {
            U b; b.u = Wf[(c * 4 + s) * 64 + lane];
            ac = __builtin_amdgcn_mfma_f32_16x16x32_bf16(a[s].s, b.s, ac, 0, 0, 0);
        }
        acc[c] = ac;
    }

    float cd[4], cs[4];
    int rows[4];
#pragma unroll
    for (int r = 0; r < 4; ++r) {
        int row = r0 + quad * 4 + r; rows[r] = row;
        bool ok = row < N_NODES;
        cd[r] = ok ? c_dst[row] : 0.f;
        cs[r] = (ok && !last) ? c_src[row] : 1.f;
    }
#pragma unroll
    for (int c = 0; c < 8; ++c) {
        int colg = c * 16 + m16;
        float b = bias[colg];
#pragma unroll
        for (int r = 0; r < 4; ++r) {
            int row = rows[r];
            if (row >= N_NODES) continue;
            float v = acc[c][r] * cd[r] + b;
            v = v > 0.f ? v : 0.f;
            if (last) out_f32[(size_t)row * DIM + colg] = v;
            else      out_bf[(size_t)row * DIM + colg] = (unsigned short)f2bf(v * cs[r]);
        }
    }
}

// Mean-pool readout on sorted graph_ids (fp32 h).
__global__ __launch_bounds__(128) void readout_kernel(
    const float* __restrict__ h, const int* __restrict__ gid,
    float* __restrict__ hg, float* __restrict__ cntg)
{
    int j  = threadIdx.x;
    int n0 = blockIdx.x * 64;
    float acc = 0.f; int cur = -1; int run = 0;
    for (int i = 0; i < 64; ++i) {
        int n = n0 + i;
        if (n >= N_NODES) break;
        int g = gid[n];
        if (g != cur) {
            if (cur >= 0) {
                atomicAdd(&hg[cur * DIM + j], acc);
                if (j == 0) atomicAdd(&cntg[cur], (float)run);
            }
            cur = g; acc = 0.f; run = 0;
        }
        acc += h[(size_t)n * DIM + j];
        run++;
    }
    if (cur >= 0) {
        atomicAdd(&hg[cur * DIM + j], acc);
        if (j == 0) atomicAdd(&cntg[cur], (float)run);
    }
}

__global__ __launch_bounds__(256) void head_kernel(
    const float* __restrict__ hg, const float* __restrict__ cntg,
    const float* __restrict__ Wc, const float* __restrict__ bc,
    float* __restrict__ out)
{
    int idx = blockIdx.x * blockDim.x + threadIdx.x;
    if (idx >= NGRAPH * NCLASS) return;
    int g = idx / NCLASS, c = idx % NCLASS;
    float inv = 1.0f / fmaxf(cntg[g], 1.0f);
    float s = 0.f;
    for (int j = 0; j < DIM; ++j) s = fmaf(hg[g * DIM + j], Wc[j * NCLASS + c], s);
    out[idx] = s * inv + bc[c];
}

// ---------------------------------------------------------------------------
extern "C" void kernel_launch(void* const* d_in, const int* in_sizes, int n_in,
                              void* d_out, int out_size, void* d_ws, size_t ws_size,
                              hipStream_t stream)
{
    const float* x   = (const float*)d_in[0];
    const float* W0  = (const float*)d_in[1];
    const float* b0  = (const float*)d_in[2];
    const float* Ws  = (const float*)d_in[3];
    const float* bs  = (const float*)d_in[4];
    const float* Wc  = (const float*)d_in[5];
    const float* bc  = (const float*)d_in[6];
    const int*   ei  = (const int*)d_in[7];
    const int*   gid = (const int*)d_in[8];
    float* out = (float*)d_out;

    char* ws = (char*)d_ws;
    size_t o = 0;
    auto alloc = [&](size_t bytes) {
        size_t r = o; o = (o + bytes + 255) & ~(size_t)255; return r;
    };
    unsigned* cntw      = (unsigned*)(ws + alloc((size_t)TEAMS * CWORDS * 4));
    unsigned* offsw     = (unsigned*)(ws + alloc((size_t)TEAMS * CWORDS * 4));
    unsigned* cnt_dense = (unsigned*)(ws + alloc((size_t)N_NODES * 4));
    float*    c_src     = (float*)(ws + alloc((size_t)N_NODES * 4));
    float*    c_dst     = (float*)(ws + alloc((size_t)N_NODES * 4));
    unsigned* colc      = (unsigned*)(ws + alloc((size_t)N_NODES * 64 * 4));
    unsigned* hs        = (unsigned*)(ws + alloc((size_t)N_NODES * 64 * 4));
    unsigned* mbuf      = (unsigned*)(ws + alloc((size_t)N_NODES * 64 * 4));
    float*    hlast     = (float*)(ws + alloc((size_t)N_NODES * DIM * 4));
    uint4*    Wf        = (uint4*)(ws + alloc((size_t)NLAYER * 2048 * 16));
    float*    hg        = (float*)(ws + alloc((size_t)NGRAPH * DIM * 4));
    float*    cntg      = (float*)(ws + alloc((size_t)NGRAPH * 4));

    hipMemsetAsync(hg,   0, (size_t)NGRAPH * DIM * 4, stream);
    hipMemsetAsync(cntg, 0, (size_t)NGRAPH * 4, stream);

    count_kernel<<<TEAMS, 1024, 0, stream>>>(ei, cntw);
    offsets_kernel<<<(N_NODES + 255) / 256, 1024, 0, stream>>>(
        cntw, offsw, cnt_dense, c_src, c_dst);
    scatter_kernel<<<TEAMS, 1024, 0, stream>>>(ei, offsw, colc);
    prescale_kernel<<<(N_NODES * 64) / 256, 256, 0, stream>>>(
        (const float2*)x, c_src, hs);
    wprep_kernel<<<(NLAYER * 2048 + 255) / 256, 256, 0, stream>>>(W0, Ws, Wf);

    const int AGG_BLOCKS = N_NODES * 64 / 256;      // 12500: one wave per quartet
    const int GEMM_BLOCKS = (N_NODES + 63) / 64;

    for (int l = 0; l < NLAYER; ++l) {
        const float* b = (l == 0) ? b0 : (bs + (size_t)(l - 1) * DIM);
        int last = (l == NLAYER - 1) ? 1 : 0;
        aggregate_kernel<<<AGG_BLOCKS, 256, 0, stream>>>(
            hs, (const uint4*)colc, cnt_dense, mbuf);
        mfma_gemm_kernel<<<GEMM_BLOCKS, 256, 0, stream>>>(
            (const uint4*)mbuf, Wf + (size_t)l * 2048, b, c_dst, c_src,
            (unsigned short*)hs, hlast, last);
    }

    readout_kernel<<<(N_NODES + 63) / 64, 128, 0, stream>>>(hlast, gid, hg, cntg);
    head_kernel<<<(NGRAPH * NCLASS + 255) / 256, 256, 0, stream>>>(hg, cntg, Wc, bc, out);
}

// Round 6
// 347.010 us; speedup vs baseline: 1.1428x; 1.1428x over previous
//
#include <hip/hip_runtime.h>

#define N_NODES 50000
#define N_EDGES 800000
#define DIM     128
#define NGRAPH  128
#define NCLASS  10
#define NLAYER  4

#define TEAMS   256
#define ESLICE  (N_EDGES / TEAMS)    // 3125 edges per team slice
#define CWORDS  12500                // 50000 nodes / 4 (nibble-packed bytes per word)

typedef __attribute__((ext_vector_type(8))) short short8;
typedef __attribute__((ext_vector_type(4))) float floatx4;

__device__ __forceinline__ unsigned f2bf(float f) {
    union { float f; unsigned u; } v; v.f = f;
    return (v.u + 0x7fffu + ((v.u >> 16) & 1u)) >> 16;   // RNE
}
__device__ __forceinline__ float bf_lo(unsigned u) { return __uint_as_float(u << 16); }
__device__ __forceinline__ float bf_hi(unsigned u) { return __uint_as_float(u & 0xffff0000u); }

// ---------------------------------------------------------------------------
// Pass 1: per-team-slice nibble histograms (in=low nibble, out=high nibble,
// one byte per node). Each edge read exactly once. Coalesced writeback.
__global__ __launch_bounds__(1024) void count_kernel(
    const int* __restrict__ ei, unsigned* __restrict__ cntw)
{
    __shared__ unsigned h[CWORDS];      // 50 KB
    int team = blockIdx.x, tid = threadIdx.x;
    for (int i = tid; i < CWORDS; i += 1024) h[i] = 0;
    __syncthreads();
    const int e0 = team * ESLICE;
    const int* __restrict__ srcp = ei;
    const int* __restrict__ dstp = ei + N_EDGES;
    for (int e = e0 + tid; e < e0 + ESLICE; e += 1024) {
        int s = srcp[e], d = dstp[e];
        atomicAdd(&h[d >> 2], 1u  << (8 * (d & 3)));   // in-count  (low nibble)
        atomicAdd(&h[s >> 2], 16u << (8 * (s & 3)));   // out-count (high nibble)
    }
    __syncthreads();
    for (int i = tid; i < CWORDS; i += 1024)
        cntw[(size_t)team * CWORDS + i] = h[i];
}

// Pass 2: per-node exclusive prefix over the 256 team counts -> exact slot
// offsets; also emits total degrees -> cnt_dense, c_src, c_dst.
__global__ __launch_bounds__(1024) void offsets_kernel(
    const unsigned* __restrict__ cntw, unsigned* __restrict__ offsw,
    unsigned* __restrict__ cnt_dense, float* __restrict__ c_src,
    float* __restrict__ c_dst)
{
    __shared__ unsigned ldsC[128 * 64];   // counts tile
    __shared__ unsigned ldsO[128 * 64];   // offsets tile
    int tid = threadIdx.x;
    int n0 = blockIdx.x * 256;
    int w0 = n0 >> 2;
    unsigned indeg = 0, outdeg = 0;
    for (int ph = 0; ph < 2; ++ph) {
        int t0 = ph * 128;
        for (int i = tid; i < 128 * 64; i += 1024) {
            int tl = i >> 6, wl = i & 63;
            int gw = w0 + wl;
            ldsC[i] = (gw < CWORDS) ? cntw[(size_t)(t0 + tl) * CWORDS + gw] : 0u;
        }
        __syncthreads();
        if (tid < 256) {
            unsigned char* ob = (unsigned char*)ldsO;
            for (int tl = 0; tl < 128; ++tl) {
                unsigned wv = ldsC[tl * 64 + (tid >> 2)];
                unsigned b = (wv >> (8 * (tid & 3))) & 255u;
                ob[tl * 256 + tid] = (unsigned char)indeg;  // exclusive prefix
                indeg  += (b & 15u);
                outdeg += (b >> 4);
            }
        }
        __syncthreads();
        for (int i = tid; i < 128 * 64; i += 1024) {
            int tl = i >> 6, wl = i & 63;
            int gw = w0 + wl;
            if (gw < CWORDS) offsw[(size_t)(t0 + tl) * CWORDS + gw] = ldsO[i];
        }
        __syncthreads();
    }
    if (tid < 256) {
        int n = n0 + tid;
        if (n < N_NODES) {
            unsigned id_ = indeg, od = outdeg;
            cnt_dense[n] = id_ > 64u ? 64u : id_;
            if (id_ < 1u) id_ = 1u;
            if (od < 1u) od = 1u;
            c_dst[n] = 1.0f / sqrtf((float)id_);
            c_src[n] = 1.0f / sqrtf((float)od);
        }
    }
}

// Pass 3: rescan slice, LDS position counters give unique local pos; write
// src directly into dense CSR at offs(team,d)+pos.
__global__ __launch_bounds__(1024) void scatter_kernel(
    const int* __restrict__ ei, const unsigned* __restrict__ offsw,
    unsigned* __restrict__ colc)
{
    __shared__ unsigned h[CWORDS];      // 50 KB pos counters (low nibble)
    int team = blockIdx.x, tid = threadIdx.x;
    for (int i = tid; i < CWORDS; i += 1024) h[i] = 0;
    __syncthreads();
    const unsigned char* __restrict__ ob =
        (const unsigned char*)offsw + (size_t)team * 50000;
    const int e0 = team * ESLICE;
    const int* __restrict__ srcp = ei;
    const int* __restrict__ dstp = ei + N_EDGES;
    for (int e = e0 + tid; e < e0 + ESLICE; e += 1024) {
        int s = srcp[e], d = dstp[e];
        unsigned old = atomicAdd(&h[d >> 2], 1u << (8 * (d & 3)));
        unsigned pos = (old >> (8 * (d & 3))) & 15u;
        unsigned slot = (unsigned)ob[d] + pos;
        if (slot < 64u) colc[(size_t)d * 64 + slot] = (unsigned)s;
    }
}

// hs(bf16 pairs) = x * c_src[row]
__global__ __launch_bounds__(256) void prescale_kernel(
    const float2* __restrict__ x, const float* __restrict__ c_src,
    unsigned* __restrict__ hs)
{
    int i = blockIdx.x * blockDim.x + threadIdx.x;   // over N*64 uints
    if (i >= N_NODES * 64) return;
    int row = i >> 6;
    float c = c_src[row];
    float2 v = x[i];
    hs[i] = f2bf(v.x * c) | (f2bf(v.y * c) << 16);
}

// m[n] = sum over in-edges of hs[src]. One wave per node; two 32-lane halves
// gather DIFFERENT edges as uint2 (512 B per load instruction = 2 rows);
// cross-half shfl_xor combine at the end. Indices broadcast from lane regs.
__global__ __launch_bounds__(256) void aggregate_kernel(
    const unsigned* __restrict__ hs, const unsigned* __restrict__ colc,
    const unsigned* __restrict__ cnt_dense, unsigned* __restrict__ m,
    int total_waves)
{
    int wid  = (blockIdx.x * blockDim.x + threadIdx.x) >> 6;
    int lane = threadIdx.x & 63;
    int half = lane >> 5;          // 0: even edges, 1: odd edges
    int hl   = lane & 31;          // feature quad: features 4*hl .. 4*hl+3
    for (int n = wid; n < N_NODES; n += total_waves) {
        unsigned deg = cnt_dense[n];
        unsigned myidx = colc[(size_t)n * 64 + lane];   // coalesced 256B
        float f0 = 0.f, f1 = 0.f, f2 = 0.f, f3 = 0.f;
        for (unsigned j = 0; j < deg; j += 8) {
#pragma unroll
            for (int k = 0; k < 4; ++k) {
                unsigned e = j + 2 * k + half;
                int sl = (e < deg) ? (int)e : 0;
                unsigned s = (unsigned)__shfl((int)myidx, sl);
                uint2 u = *(const uint2*)(hs + (size_t)s * 64 + hl * 2);
                if (e >= deg) { u.x = 0u; u.y = 0u; }
                f0 += bf_lo(u.x); f1 += bf_hi(u.x);
                f2 += bf_lo(u.y); f3 += bf_hi(u.y);
            }
        }
        f0 += __shfl_xor(f0, 32); f1 += __shfl_xor(f1, 32);
        f2 += __shfl_xor(f2, 32); f3 += __shfl_xor(f3, 32);
        if (half == 0) {
            uint2 r;
            r.x = f2bf(f0) | (f2bf(f1) << 16);
            r.y = f2bf(f2) | (f2bf(f3) << 16);
            *(uint2*)(m + (size_t)n * 64 + hl * 2) = r;
        }
    }
}

// Pre-swizzle W into MFMA B-fragment order, bf16.
__global__ __launch_bounds__(256) void wprep_kernel(
    const float* __restrict__ W0, const float* __restrict__ Ws,
    uint4* __restrict__ Wf)
{
    int t = blockIdx.x * blockDim.x + threadIdx.x;
    if (t >= NLAYER * 2048) return;
    int layer = t >> 11;
    int rem = t & 2047;
    int lane = rem & 63;
    int s = (rem >> 6) & 3;
    int c = rem >> 8;
    int quad = lane >> 4, colw = c * 16 + (lane & 15);
    int k0 = s * 32 + quad * 8;
    const float* W = (layer == 0) ? W0 : Ws + (size_t)(layer - 1) * DIM * DIM;
    uint4 p;
    unsigned* pp = (unsigned*)&p;
#pragma unroll
    for (int j = 0; j < 4; ++j) {
        unsigned lo = f2bf(W[(size_t)(k0 + 2 * j) * DIM + colw]);
        unsigned hi = f2bf(W[(size_t)(k0 + 2 * j + 1) * DIM + colw]);
        pp[j] = lo | (hi << 16);
    }
    Wf[t] = p;
}

// Hout = relu(c_dst[r]*(M@W) + b) [* c_src[r] if !last], MFMA 16x16x32 bf16.
__global__ __launch_bounds__(256) void mfma_gemm_kernel(
    const uint4* __restrict__ Mb, const uint4* __restrict__ Wf,
    const float* __restrict__ bias, const float* __restrict__ c_dst,
    const float* __restrict__ c_src, unsigned short* __restrict__ out_bf,
    float* __restrict__ out_f32, int last)
{
    int tid = threadIdx.x;
    int wave = tid >> 6, lane = tid & 63;
    int quad = lane >> 4, m16 = lane & 15;
    int r0 = blockIdx.x * 64 + wave * 16;

    int rA = r0 + m16; if (rA >= N_NODES) rA = N_NODES - 1;
    const uint4* pA = Mb + (size_t)rA * 16 + quad;
    union U { uint4 u; short8 s; };
    U a[4];
#pragma unroll
    for (int s = 0; s < 4; ++s) a[s].u = pA[s * 4];

    floatx4 acc[8];
#pragma unroll
    for (int c = 0; c < 8; ++c) {
        floatx4 ac = {0.f, 0.f, 0.f, 0.f};
#pragma unroll
        for (int s = 0; s < 4; ++s) {
            U b; b.u = Wf[(c * 4 + s) * 64 + lane];
            ac = __builtin_amdgcn_mfma_f32_16x16x32_bf16(a[s].s, b.s, ac, 0, 0, 0);
        }
        acc[c] = ac;
    }

    float cd[4], cs[4];
    int rows[4];
#pragma unroll
    for (int r = 0; r < 4; ++r) {
        int row = r0 + quad * 4 + r; rows[r] = row;
        bool ok = row < N_NODES;
        cd[r] = ok ? c_dst[row] : 0.f;
        cs[r] = (ok && !last) ? c_src[row] : 1.f;
    }
#pragma unroll
    for (int c = 0; c < 8; ++c) {
        int colg = c * 16 + m16;
        float b = bias[colg];
#pragma unroll
        for (int r = 0; r < 4; ++r) {
            int row = rows[r];
            if (row >= N_NODES) continue;
            float v = acc[c][r] * cd[r] + b;
            v = v > 0.f ? v : 0.f;
            if (last) out_f32[(size_t)row * DIM + colg] = v;
            else      out_bf[(size_t)row * DIM + colg] = (unsigned short)f2bf(v * cs[r]);
        }
    }
}

// Mean-pool readout on sorted graph_ids (fp32 h).
__global__ __launch_bounds__(128) void readout_kernel(
    const float* __restrict__ h, const int* __restrict__ gid,
    float* __restrict__ hg, float* __restrict__ cntg)
{
    int j  = threadIdx.x;
    int n0 = blockIdx.x * 64;
    float acc = 0.f; int cur = -1; int run = 0;
    for (int i = 0; i < 64; ++i) {
        int n = n0 + i;
        if (n >= N_NODES) break;
        int g = gid[n];
        if (g != cur) {
            if (cur >= 0) {
                atomicAdd(&hg[cur * DIM + j], acc);
                if (j == 0) atomicAdd(&cntg[cur], (float)run);
            }
            cur = g; acc = 0.f; run = 0;
        }
        acc += h[(size_t)n * DIM + j];
        run++;
    }
    if (cur >= 0) {
        atomicAdd(&hg[cur * DIM + j], acc);
        if (j == 0) atomicAdd(&cntg[cur], (float)run);
    }
}

__global__ __launch_bounds__(256) void head_kernel(
    const float* __restrict__ hg, const float* __restrict__ cntg,
    const float* __restrict__ Wc, const float* __restrict__ bc,
    float* __restrict__ out)
{
    int idx = blockIdx.x * blockDim.x + threadIdx.x;
    if (idx >= NGRAPH * NCLASS) return;
    int g = idx / NCLASS, c = idx % NCLASS;
    float inv = 1.0f / fmaxf(cntg[g], 1.0f);
    float s = 0.f;
    for (int j = 0; j < DIM; ++j) s = fmaf(hg[g * DIM + j], Wc[j * NCLASS + c], s);
    out[idx] = s * inv + bc[c];
}

// ---------------------------------------------------------------------------
extern "C" void kernel_launch(void* const* d_in, const int* in_sizes, int n_in,
                              void* d_out, int out_size, void* d_ws, size_t ws_size,
                              hipStream_t stream)
{
    const float* x   = (const float*)d_in[0];
    const float* W0  = (const float*)d_in[1];
    const float* b0  = (const float*)d_in[2];
    const float* Ws  = (const float*)d_in[3];
    const float* bs  = (const float*)d_in[4];
    const float* Wc  = (const float*)d_in[5];
    const float* bc  = (const float*)d_in[6];
    const int*   ei  = (const int*)d_in[7];
    const int*   gid = (const int*)d_in[8];
    float* out = (float*)d_out;

    char* ws = (char*)d_ws;
    size_t o = 0;
    auto alloc = [&](size_t bytes) {
        size_t r = o; o = (o + bytes + 255) & ~(size_t)255; return r;
    };
    unsigned* cntw      = (unsigned*)(ws + alloc((size_t)TEAMS * CWORDS * 4));
    unsigned* offsw     = (unsigned*)(ws + alloc((size_t)TEAMS * CWORDS * 4));
    unsigned* cnt_dense = (unsigned*)(ws + alloc((size_t)N_NODES * 4));
    float*    c_src     = (float*)(ws + alloc((size_t)N_NODES * 4));
    float*    c_dst     = (float*)(ws + alloc((size_t)N_NODES * 4));
    unsigned* colc      = (unsigned*)(ws + alloc((size_t)N_NODES * 64 * 4));
    unsigned* hs        = (unsigned*)(ws + alloc((size_t)N_NODES * 64 * 4));
    unsigned* mbuf      = (unsigned*)(ws + alloc((size_t)N_NODES * 64 * 4));
    float*    hlast     = (float*)(ws + alloc((size_t)N_NODES * DIM * 4));
    uint4*    Wf        = (uint4*)(ws + alloc((size_t)NLAYER * 2048 * 16));
    float*    hg        = (float*)(ws + alloc((size_t)NGRAPH * DIM * 4));
    float*    cntg      = (float*)(ws + alloc((size_t)NGRAPH * 4));

    hipMemsetAsync(hg,   0, (size_t)NGRAPH * DIM * 4, stream);
    hipMemsetAsync(cntg, 0, (size_t)NGRAPH * 4, stream);

    count_kernel<<<TEAMS, 1024, 0, stream>>>(ei, cntw);
    offsets_kernel<<<(N_NODES + 255) / 256, 1024, 0, stream>>>(
        cntw, offsw, cnt_dense, c_src, c_dst);
    scatter_kernel<<<TEAMS, 1024, 0, stream>>>(ei, offsw, colc);
    prescale_kernel<<<(N_NODES * 64) / 256, 256, 0, stream>>>(
        (const float2*)x, c_src, hs);
    wprep_kernel<<<(NLAYER * 2048 + 255) / 256, 256, 0, stream>>>(W0, Ws, Wf);

    const int AGG_BLOCKS = 2048;
    const int TOTAL_WAVES = AGG_BLOCKS * 4;
    const int GEMM_BLOCKS = (N_NODES + 63) / 64;

    for (int l = 0; l < NLAYER; ++l) {
        const float* b = (l == 0) ? b0 : (bs + (size_t)(l - 1) * DIM);
        int last = (l == NLAYER - 1) ? 1 : 0;
        aggregate_kernel<<<AGG_BLOCKS, 256, 0, stream>>>(
            hs, colc, cnt_dense, mbuf, TOTAL_WAVES);
        mfma_gemm_kernel<<<GEMM_BLOCKS, 256, 0, stream>>>(
            (const uint4*)mbuf, Wf + (size_t)l * 2048, b, c_dst, c_src,
            (unsigned short*)hs, hlast, last);
    }

    readout_kernel<<<(N_NODES + 63) / 64, 128, 0, stream>>>(hlast, gid, hg, cntg);
    head_kernel<<<(NGRAPH * NCLASS + 255) / 256, 256, 0, stream>>>(hg, cntg, Wc, bc, out);
}